// Round 16
// baseline (147.819 us; speedup 1.0000x reference)
//
#include <hip/hip_runtime.h>

// MCA linear attention, fp32. B=8, C=64, H=W=160, P=8 heads, d=8, N=25600.
#define NPIX  25600
#define NB    8
#define NCH   100    // k1 pixel chunks per batch (256 px each)
#define CPX   256    // k1 chunk pixels (64 lanes x 4 px)
#define KCH   200    // k3 pixel chunks per batch (128 px each)
#define KPX   128    // k3 chunk pixels (64 lanes x 2 px)
#define EPSV  1e-6f

// workspace layout (float offsets)
#define WS_WKVT  0        // [8 h][64 c][16]  (8 wk rows, 8 wv rows, transposed)
#define WS_WQT   8192     // [8 h][64 c][8]
#define WS_BKV   12288    // [8 h][16]
#define WS_BQ    12416    // [8 h][8]
#define WS_PART  12480    // [64 bh][100 ch][72]  (contiguous 72 per chunk)
#define WS_G     473280   // [8 b][64 pm][64 o]
#define WS_KSE   506048   // [8 b][8 p][8 m]

__device__ __forceinline__ float softplus_(float x) {
  // hw v_exp/v_log path; for x>20, log(1+e^x)==x to fp32 precision
  return (x > 20.0f) ? x : __logf(1.0f + __expf(x));
}

// DPP wave64 sum: row_shr 1/2/4/8 then row_bcast:15 (rows 1,3) and
// row_bcast:31 (rows 2,3). Full sum lands in lane 63. old=0 makes masked /
// invalid lanes contribute 0 regardless of bound_ctrl interpretation.
template <int CTRL, int RMASK>
__device__ __forceinline__ float dpp_add(float x) {
  int y = __builtin_amdgcn_update_dpp(0, __float_as_int(x), CTRL, RMASK, 0xf, false);
  return x + __int_as_float(y);
}
__device__ __forceinline__ float wave_sum63(float x) {
  x = dpp_add<0x111, 0xf>(x);   // row_shr:1
  x = dpp_add<0x112, 0xf>(x);   // row_shr:2
  x = dpp_add<0x114, 0xf>(x);   // row_shr:4
  x = dpp_add<0x118, 0xf>(x);   // row_shr:8
  x = dpp_add<0x142, 0xa>(x);   // row_bcast:15 -> rows 1,3
  x = dpp_add<0x143, 0xc>(x);   // row_bcast:31 -> rows 2,3
  return x;                     // lane 63 holds the wave total
}

// ---------------- kernel 0: pack weights/biases transposed ----------------
__global__ void k0_pack(const float* __restrict__ wq_high, const float* __restrict__ bq_high,
                        const float* __restrict__ wq_low,  const float* __restrict__ bq_low,
                        const float* __restrict__ wk, const float* __restrict__ bk,
                        const float* __restrict__ wv, const float* __restrict__ bv,
                        float* __restrict__ ws) {
  const int tid = threadIdx.x;
  for (int e = tid; e < 8192; e += 256) {        // wkvT[h][c][j]
    int j = e & 15, c = (e >> 4) & 63, h = e >> 10, m = j & 7;
    float v = (j < 8) ? wk[(h * 8 + m) * 64 + c] : wv[(h * 8 + m) * 64 + c];
    ws[WS_WKVT + e] = v;
  }
  for (int e = tid; e < 4096; e += 256) {        // wqT[h][c][m]
    int m = e & 7, c = (e >> 3) & 63, h = e >> 9;
    float v = (h < 4) ? wq_high[(h * 8 + m) * 64 + c]
                      : wq_low[((h - 4) * 8 + m) * 64 + c];
    ws[WS_WQT + e] = v;
  }
  for (int e = tid; e < 128; e += 256) {         // bkv[h][j]
    int j = e & 15, h = e >> 4, m = j & 7;
    ws[WS_BKV + e] = (j < 8) ? bk[h * 8 + m] : bv[h * 8 + m];
  }
  for (int e = tid; e < 64; e += 256) {          // bq[h][m]
    int m = e & 7, h = e >> 3;
    ws[WS_BQ + e] = (h < 4) ? bq_high[h * 8 + m] : bq_low[(h - 4) * 8 + m];
  }
}

// ---------------- kernel 1: k,v -> per-chunk partial attn/ksum ----------------
// Measured-best structure (R9/R12/R15, 65 us): 256 threads = 4 waves; block
// (chunk, b, half) -> wave w = head half*4+w. Lane owns 4 px (float4 loads).
// Weights via wave-uniform s_loads (x is vm-counter, w is lgkm -- independent,
// no mixing hazard); row-streaming + DPP reduce; scalar fmaf.
__global__ __attribute__((amdgpu_waves_per_eu(1, 8)))
void k1_kv(const float* __restrict__ low,
           const float* __restrict__ ws,
           float* __restrict__ part) {
  const int b = blockIdx.y >> 1, half = blockIdx.y & 1, chunk = blockIdx.x;
  const int tid = threadIdx.x, lane = tid & 63;
  const int wu = __builtin_amdgcn_readfirstlane(half * 4 + (tid >> 6));
  const float* lowb = low + (size_t)b * 64 * NPIX + chunk * CPX;
  const float* wt = ws + WS_WKVT + wu * 1024;    // wave-uniform -> s_load
  const float* bias = ws + WS_BKV + wu * 16;
  float ka[8][4], va[8][4];
#pragma unroll
  for (int m = 0; m < 8; m++) {
    float bkm = bias[m], bvm = bias[8 + m];
#pragma unroll
    for (int px = 0; px < 4; px++) { ka[m][px] = bkm; va[m][px] = bvm; }
  }
#pragma unroll 8
  for (int c = 0; c < 64; c++) {
    float4 x = reinterpret_cast<const float4*>(lowb + (size_t)c * NPIX)[lane];
    const float* wr = wt + c * 16;
#pragma unroll
    for (int m = 0; m < 8; m++) {
      float wkm = wr[m], wvm = wr[8 + m];
      ka[m][0] = fmaf(wkm, x.x, ka[m][0]);
      ka[m][1] = fmaf(wkm, x.y, ka[m][1]);
      ka[m][2] = fmaf(wkm, x.z, ka[m][2]);
      ka[m][3] = fmaf(wkm, x.w, ka[m][3]);
      va[m][0] = fmaf(wvm, x.x, va[m][0]);
      va[m][1] = fmaf(wvm, x.y, va[m][1]);
      va[m][2] = fmaf(wvm, x.z, va[m][2]);
      va[m][3] = fmaf(wvm, x.w, va[m][3]);
    }
  }
#pragma unroll
  for (int m = 0; m < 8; m++)
#pragma unroll
    for (int px = 0; px < 4; px++) ka[m][px] = softplus_(ka[m][px]);
  float* pb = part + ((size_t)(b * 8 + wu) * NCH + chunk) * 72;
  // attn rows, streamed: products -> DPP reduce -> lane-63 store, row by row
#pragma unroll
  for (int m = 0; m < 8; m++) {
    float r[8];
#pragma unroll
    for (int c = 0; c < 8; c++) {
      float a = ka[m][0] * va[c][0];
      a = fmaf(ka[m][1], va[c][1], a);
      a = fmaf(ka[m][2], va[c][2], a);
      r[c] = fmaf(ka[m][3], va[c][3], a);
    }
#pragma unroll
    for (int c = 0; c < 8; c++) r[c] = wave_sum63(r[c]);
    if (lane == 63) {
      reinterpret_cast<float4*>(&pb[m * 8])[0] = make_float4(r[0], r[1], r[2], r[3]);
      reinterpret_cast<float4*>(&pb[m * 8])[1] = make_float4(r[4], r[5], r[6], r[7]);
    }
  }
  // ksum row
  {
    float r[8];
#pragma unroll
    for (int m = 0; m < 8; m++)
      r[m] = (ka[m][0] + ka[m][1]) + (ka[m][2] + ka[m][3]);
#pragma unroll
    for (int m = 0; m < 8; m++) r[m] = wave_sum63(r[m]);
    if (lane == 63) {
      reinterpret_cast<float4*>(&pb[64])[0] = make_float4(r[0], r[1], r[2], r[3]);
      reinterpret_cast<float4*>(&pb[64])[1] = make_float4(r[4], r[5], r[6], r[7]);
    }
  }
}

// ---------------- kernel 2: reduce partials, build G and ksumE ----------------
// 64 blocks (b*8+p) x 256 threads; chunk loop split 4-way across sub-waves.
__global__ void k2_g(const float* __restrict__ part, const float* __restrict__ wo,
                     float* __restrict__ ws) {
  const int b = blockIdx.x >> 3, p = blockIdx.x & 7;
  const int tid = threadIdx.x, lane = tid & 63, sub = tid >> 6;
  __shared__ float red[4][72];
  __shared__ float attnL[72];
  const float* src = part + (size_t)(b * 8 + p) * NCH * 72;
  float s0 = 0.0f, s1 = 0.0f;
  for (int ch = sub * (NCH / 4); ch < (sub + 1) * (NCH / 4); ch++) {
    s0 += src[ch * 72 + lane];
    if (lane < 8) s1 += src[ch * 72 + 64 + lane];
  }
  red[sub][lane] = s0;
  if (lane < 8) red[sub][64 + lane] = s1;
  __syncthreads();
  if (tid < 72) attnL[tid] = (red[0][tid] + red[1][tid]) + (red[2][tid] + red[3][tid]);
  __syncthreads();
  if (tid >= 64) {
    if (tid < 72) ws[WS_KSE + (b * 8 + p) * 8 + (tid - 64)] = attnL[tid] + EPSV;
    return;
  }
  const int o = tid;
  float wrow[8];
#pragma unroll
  for (int c = 0; c < 8; c++) wrow[c] = wo[o * 64 + p * 8 + c];
  float* Gp = ws + WS_G + (size_t)(b * 64 + p * 8) * 64;
#pragma unroll
  for (int m = 0; m < 8; m++) {
    float g = 0.0f;
#pragma unroll
    for (int c = 0; c < 8; c++) g = fmaf(attnL[m * 8 + c], wrow[c], g);
    Gp[m * 64 + o] = g;
  }
}

// ---------------- kernel 3: q, norm, fused out-projection ----------------
// R13's k3 (implied ~57 us, masked in R13 by the k1 regression): all uniform
// operands staged in LDS: wq (16KB, A) + G (16KB, B) + qsL (32KB) = 64KB.
// Why it wins: phase B previously mixed ds_read (qsL) with s_load (G) --
// both lgkmcnt, but SMEM returns out-of-order vs DS, forcing conservative
// lgkmcnt(0) per iteration. All-DS gives precise counted waits -> pipelined.
__global__ __attribute__((amdgpu_waves_per_eu(1, 8)))
void k3_main(const float* __restrict__ high,
             const float* __restrict__ low,
             const float* __restrict__ ws,
             const float* __restrict__ bo,
             float* __restrict__ out) {
  const int b = blockIdx.y, chunk = blockIdx.x;
  const int tid = threadIdx.x, lane = tid & 63;
  const int wu = __builtin_amdgcn_readfirstlane(tid >> 6);
  __shared__ float qsL[64 * KPX];                // 32 KB [64 pm][128 px]
  __shared__ float wqL[4096];                    // 16 KB [8 h][64 c][8]
  __shared__ float GL[4096];                     // 16 KB [64 pm][64 o]
  {
    const float4* ws1 = reinterpret_cast<const float4*>(ws + WS_WQT);
    const float4* ws2 = reinterpret_cast<const float4*>(ws + WS_G + (size_t)b * 4096);
    float4* d1 = reinterpret_cast<float4*>(wqL);
    float4* d2 = reinterpret_cast<float4*>(GL);
#pragma unroll
    for (int i = 0; i < 2; i++) {
      d1[tid + i * 512] = ws1[tid + i * 512];
      d2[tid + i * 512] = ws2[tid + i * 512];
    }
  }
  const float* srcb = ((wu < 4) ? high : low) + (size_t)b * 64 * NPIX + chunk * KPX;
  const float* wq  = wqL + wu * 512;             // wave-uniform -> ds broadcast
  const float* bq  = ws + WS_BQ + wu * 8;
  const float* kse = ws + WS_KSE + (b * 8 + wu) * 8;
  float qa[8][2];
#pragma unroll
  for (int m = 0; m < 8; m++) { qa[m][0] = bq[m]; qa[m][1] = bq[m]; }
  __syncthreads();
#pragma unroll 8
  for (int c = 0; c < 64; c++) {
    float2 x = reinterpret_cast<const float2*>(srcb + (size_t)c * NPIX)[lane];
    const float* wr = wq + c * 8;
    float4 w4 = reinterpret_cast<const float4*>(wr)[0];
    float4 w8 = reinterpret_cast<const float4*>(wr)[1];
    const float wm[8] = {w4.x, w4.y, w4.z, w4.w, w8.x, w8.y, w8.z, w8.w};
#pragma unroll
    for (int m = 0; m < 8; m++) {
      qa[m][0] = fmaf(wm[m], x.x, qa[m][0]);
      qa[m][1] = fmaf(wm[m], x.y, qa[m][1]);
    }
  }
  float s0 = 0.0f, s1 = 0.0f;
#pragma unroll
  for (int m = 0; m < 8; m++) {
    float km = kse[m];
    qa[m][0] = softplus_(qa[m][0]);
    qa[m][1] = softplus_(qa[m][1]);
    s0 = fmaf(qa[m][0], km, s0);
    s1 = fmaf(qa[m][1], km, s1);
  }
  const float r0 = 1.0f / s0, r1 = 1.0f / s1;
#pragma unroll
  for (int m = 0; m < 8; m++) {
    reinterpret_cast<float2*>(&qsL[(wu * 8 + m) * KPX])[lane] =
        make_float2(qa[m][0] * r0, qa[m][1] * r1);
  }
  __syncthreads();
  float acc[8][2];
#pragma unroll
  for (int j = 0; j < 8; j++) { acc[j][0] = bo[wu * 8 + j]; acc[j][1] = acc[j][0]; }
#pragma unroll 8
  for (int pm = 0; pm < 64; pm++) {
    float2 qv = reinterpret_cast<const float2*>(&qsL[pm * KPX])[lane];
    const float* gr = GL + pm * 64 + wu * 8;     // wave-uniform -> ds broadcast
    float4 g4 = reinterpret_cast<const float4*>(gr)[0];
    float4 g8 = reinterpret_cast<const float4*>(gr)[1];
    const float gm[8] = {g4.x, g4.y, g4.z, g4.w, g8.x, g8.y, g8.z, g8.w};
#pragma unroll
    for (int j = 0; j < 8; j++) {
      acc[j][0] = fmaf(gm[j], qv.x, acc[j][0]);
      acc[j][1] = fmaf(gm[j], qv.y, acc[j][1]);
    }
  }
  float* ob = out + (size_t)(b * 64 + wu * 8) * NPIX + chunk * KPX;
#pragma unroll
  for (int j = 0; j < 8; j++) {
    reinterpret_cast<float2*>(ob + (size_t)j * NPIX)[lane] =
        make_float2(acc[j][0], acc[j][1]);
  }
}

extern "C" void kernel_launch(void* const* d_in, const int* in_sizes, int n_in,
                              void* d_out, int out_size, void* d_ws, size_t ws_size,
                              hipStream_t stream) {
  const float* high    = (const float*)d_in[0];
  const float* low     = (const float*)d_in[1];
  const float* wq_high = (const float*)d_in[2];
  const float* bq_high = (const float*)d_in[3];
  const float* wq_low  = (const float*)d_in[4];
  const float* bq_low  = (const float*)d_in[5];
  const float* wk      = (const float*)d_in[6];
  const float* bk      = (const float*)d_in[7];
  const float* wv      = (const float*)d_in[8];
  const float* bv      = (const float*)d_in[9];
  const float* wo      = (const float*)d_in[10];
  const float* bo      = (const float*)d_in[11];
  float* ws  = (float*)d_ws;
  float* out = (float*)d_out;

  k0_pack<<<1, 256, 0, stream>>>(wq_high, bq_high, wq_low, bq_low, wk, bk, wv, bv, ws);
  dim3 grid1(NCH, NB * 2);
  k1_kv<<<grid1, 256, 0, stream>>>(low, ws, ws + WS_PART);
  k2_g<<<64, 256, 0, stream>>>(ws + WS_PART, wo, ws);
  dim3 grid3(KCH, NB);
  k3_main<<<grid3, 512, 0, stream>>>(high, low, ws, bo, out);
}

// Round 17
// 122.692 us; speedup vs baseline: 1.2048x; 1.2048x over previous
//
#include <hip/hip_runtime.h>

// MCA linear attention. B=8, C=64, H=W=160, P=8 heads, d=8, N=25600.
// k1 rewritten on MFMA (split-bf16, fp32-accurate). k2/k3 = proven R15 forms.
#define NPIX  25600
#define NB    8
#define NCH   200    // k1/k3 pixel chunks per batch (128 px each)
#define KPX   128    // chunk pixels
#define EPSV  1e-6f

// workspace layout (float offsets)
#define WS_WKVT  0        // legacy pack (unused by new k1)
#define WS_WQT   8192     // [8 h][64 c][8]   (k3)
#define WS_BKV   12288    // legacy
#define WS_BQ    12416    // [8 h][8]         (k3)
#define WS_PART  12480    // [64 bh][200 ch][72]
#define WS_G     934080   // [8 b][64 pm][64 o]
#define WS_KSE   966848   // [8 b][8 p][8 m]
#define WS_WKVM  966912   // MFMA W frags: 32 frags x 64 lanes x 8 bf16 (8192 f)
#define WS_BKVM  975104   // [8 mt][16 row] bias

typedef __attribute__((ext_vector_type(8))) short short8v;
typedef __attribute__((ext_vector_type(4))) float f32x4v;

__device__ __forceinline__ unsigned short f2bf(float x) {   // RNE fp32->bf16 bits
  unsigned u = __float_as_uint(x);
  return (unsigned short)((u + 0x7FFFu + ((u >> 16) & 1u)) >> 16);
}
__device__ __forceinline__ float bf2f(unsigned short h) {
  return __uint_as_float(((unsigned)h) << 16);
}

__device__ __forceinline__ float softplus_(float x) {
  return (x > 20.0f) ? x : __logf(1.0f + __expf(x));
}

// ---------------- kernel 0: pack weights/biases ----------------
__global__ void k0_pack(const float* __restrict__ wq_high, const float* __restrict__ bq_high,
                        const float* __restrict__ wq_low,  const float* __restrict__ bq_low,
                        const float* __restrict__ wk, const float* __restrict__ bk,
                        const float* __restrict__ wv, const float* __restrict__ bv,
                        float* __restrict__ ws) {
  const int tid = threadIdx.x;
  for (int e = tid; e < 4096; e += 256) {        // wqT[h][c][m] (k3)
    int m = e & 7, c = (e >> 3) & 63, h = e >> 9;
    float v = (h < 4) ? wq_high[(h * 8 + m) * 64 + c]
                      : wq_low[((h - 4) * 8 + m) * 64 + c];
    ws[WS_WQT + e] = v;
  }
  for (int e = tid; e < 64; e += 256) {          // bq[h][m] (k3)
    int m = e & 7, h = e >> 3;
    ws[WS_BQ + e] = (h < 4) ? bq_high[h * 8 + m] : bq_low[(h - 4) * 8 + m];
  }
  // MFMA A-frags for Wkv, split-bf16. frag = mt*4 + ks*2 + sp; lane-linear 16B.
  // M-tile mt<4: K rows of heads (2mt, 2mt+1); mt>=4: V rows of heads (2(mt-4), ...).
  // A layout: lane l holds A[row = l%16][k32 = (l/16)*8 + j], c = ks*32 + k32.
  unsigned short* wmp = (unsigned short*)(ws + WS_WKVM);
  for (int e = tid; e < 16384; e += 256) {
    int j = e & 7, l = (e >> 3) & 63, frag = e >> 9;
    int sp = frag & 1, ks = (frag >> 1) & 1, mt = frag >> 2;
    int row = l & 15, k32 = (l >> 4) * 8 + j, c = ks * 32 + k32;
    int head = (mt & 3) * 2 + (row >> 3), m = row & 7;
    float wv_ = (mt < 4) ? wk[(head * 8 + m) * 64 + c] : wv[(head * 8 + m) * 64 + c];
    unsigned short hb = f2bf(wv_);
    wmp[e] = (sp == 0) ? hb : f2bf(wv_ - bf2f(hb));
  }
  for (int e = tid; e < 128; e += 256) {         // bias per feature row
    int mt = e >> 4, row = e & 15;
    int head = (mt & 3) * 2 + (row >> 3), m = row & 7;
    ws[WS_BKVM + e] = (mt < 4) ? bk[head * 8 + m] : bv[head * 8 + m];
  }
}

// ---------------- kernel 1: MFMA k,v + attn partials ----------------
// 256 thr = 4 waves; block = (chunk 128px, b). GEMM1: KV[128x64].X[64x128]
// (wave w owns 32-px strip; split-bf16 = 3 MFMA per product). softplus on K,
// bias added, result to 64KB XOR-swizzled LDS. GEMM2: per head attn[8x8] =
// K_h . V_h^T contracting px via MFMA, B col 8 = ones -> ksum free.
__global__ __attribute__((amdgpu_waves_per_eu(1, 8)))
void k1_kv(const float* __restrict__ low,
           const float* __restrict__ ws,
           float* __restrict__ part) {
  const int b = blockIdx.y, chunk = blockIdx.x;
  const int tid = threadIdx.x, lane = tid & 63;
  const int w = __builtin_amdgcn_readfirstlane(tid >> 6);
  const int l15 = lane & 15, lg = lane >> 4;
  __shared__ float kvL[16384];                   // [128 feat][128 px] swizzled
  const float* lowb = low + (size_t)b * 64 * NPIX + chunk * KPX + w * 32;
  // ---- X B-frags (fp32 gather -> split bf16) ----
  short8v xhi[2][2], xlo[2][2];
#pragma unroll
  for (int nt = 0; nt < 2; nt++)
#pragma unroll
    for (int ks = 0; ks < 2; ks++) {
      const float* xp = lowb + (size_t)(ks * 32 + lg * 8) * NPIX + nt * 16 + l15;
      float xs[8];
#pragma unroll
      for (int j = 0; j < 8; j++) xs[j] = xp[(size_t)j * NPIX];
#pragma unroll
      for (int j = 0; j < 8; j++) {
        unsigned short h = f2bf(xs[j]);
        xhi[nt][ks][j] = (short)h;
        xlo[nt][ks][j] = (short)f2bf(xs[j] - bf2f(h));
      }
    }
  const unsigned short* wm = (const unsigned short*)(ws + WS_WKVM);
  const float* bm = ws + WS_BKVM;
  // ---- GEMM1 ----
#pragma unroll
  for (int mt = 0; mt < 8; mt++) {
    f32x4v a0 = {0.f, 0.f, 0.f, 0.f}, a1 = {0.f, 0.f, 0.f, 0.f};
#pragma unroll
    for (int ks = 0; ks < 2; ks++) {
      short8v whi = *(const short8v*)(wm + (((mt * 4 + ks * 2 + 0) * 64) + lane) * 8);
      short8v wlo = *(const short8v*)(wm + (((mt * 4 + ks * 2 + 1) * 64) + lane) * 8);
      a0 = __builtin_amdgcn_mfma_f32_16x16x32_bf16(whi, xhi[0][ks], a0, 0, 0, 0);
      a0 = __builtin_amdgcn_mfma_f32_16x16x32_bf16(whi, xlo[0][ks], a0, 0, 0, 0);
      a0 = __builtin_amdgcn_mfma_f32_16x16x32_bf16(wlo, xhi[0][ks], a0, 0, 0, 0);
      a1 = __builtin_amdgcn_mfma_f32_16x16x32_bf16(whi, xhi[1][ks], a1, 0, 0, 0);
      a1 = __builtin_amdgcn_mfma_f32_16x16x32_bf16(whi, xlo[1][ks], a1, 0, 0, 0);
      a1 = __builtin_amdgcn_mfma_f32_16x16x32_bf16(wlo, xhi[1][ks], a1, 0, 0, 0);
    }
#pragma unroll
    for (int r = 0; r < 4; r++) {
      const int row = mt * 16 + lg * 4 + r;
      const float bb = bm[row];
      float v0 = a0[r] + bb, v1 = a1[r] + bb;
      if (mt < 4) { v0 = softplus_(v0); v1 = softplus_(v1); }
      const int px0 = w * 32 + l15, px1 = w * 32 + 16 + l15;
      kvL[row * 128 + ((((px0 >> 2) ^ (row & 7))) << 2) + (px0 & 3)] = v0;
      kvL[row * 128 + ((((px1 >> 2) ^ (row & 7))) << 2) + (px1 & 3)] = v1;
    }
  }
  __syncthreads();
  // ---- GEMM2: wave w -> heads w, w+4 ----
  const int col = l15;
#pragma unroll
  for (int hh = 0; hh < 2; hh++) {
    const int h = w + hh * 4;
    f32x4v acc = {0.f, 0.f, 0.f, 0.f};
    const int arow = h * 8 + (l15 & 7);          // K feat (rows 8-15 dup, ignored)
    const int brow = 64 + h * 8 + (col < 8 ? col : 0);
#pragma unroll
    for (int ks = 0; ks < 4; ks++) {
      const int pxl = ks * 32 + lg * 8;
      const int sA = arow & 7;
      float4 af0 = *(const float4*)&kvL[arow * 128 + (((pxl >> 2) ^ sA) << 2)];
      float4 af1 = *(const float4*)&kvL[arow * 128 + ((((pxl >> 2) + 1) ^ sA) << 2)];
      float as[8] = {af0.x, af0.y, af0.z, af0.w, af1.x, af1.y, af1.z, af1.w};
      float bs[8];
      if (col < 8) {
        const int sB = brow & 7;
        float4 bf0 = *(const float4*)&kvL[brow * 128 + (((pxl >> 2) ^ sB) << 2)];
        float4 bf1 = *(const float4*)&kvL[brow * 128 + ((((pxl >> 2) + 1) ^ sB) << 2)];
        bs[0]=bf0.x; bs[1]=bf0.y; bs[2]=bf0.z; bs[3]=bf0.w;
        bs[4]=bf1.x; bs[5]=bf1.y; bs[6]=bf1.z; bs[7]=bf1.w;
      } else {
        const float fill = (col == 8) ? 1.0f : 0.0f;
#pragma unroll
        for (int j = 0; j < 8; j++) bs[j] = fill;
      }
      short8v ahi, alo, bhi, blo;
#pragma unroll
      for (int j = 0; j < 8; j++) {
        unsigned short ha = f2bf(as[j]);
        ahi[j] = (short)ha; alo[j] = (short)f2bf(as[j] - bf2f(ha));
        unsigned short hb = f2bf(bs[j]);
        bhi[j] = (short)hb; blo[j] = (short)f2bf(bs[j] - bf2f(hb));
      }
      acc = __builtin_amdgcn_mfma_f32_16x16x32_bf16(ahi, bhi, acc, 0, 0, 0);
      acc = __builtin_amdgcn_mfma_f32_16x16x32_bf16(ahi, blo, acc, 0, 0, 0);
      acc = __builtin_amdgcn_mfma_f32_16x16x32_bf16(alo, bhi, acc, 0, 0, 0);
    }
    if (lane < 32 && col <= 8) {                 // rows 0-7 valid, cols 0-8
      float* pb = part + ((size_t)(b * 8 + h) * NCH + chunk) * 72;
#pragma unroll
      for (int r = 0; r < 4; r++) {
        const int rr = lg * 4 + r;
        if (col < 8) pb[rr * 8 + col] = acc[r];
        else         pb[64 + rr] = acc[r];
      }
    }
  }
}

// ---------------- kernel 2: reduce partials, build G and ksumE ----------------
__global__ void k2_g(const float* __restrict__ part, const float* __restrict__ wo,
                     float* __restrict__ ws) {
  const int b = blockIdx.x >> 3, p = blockIdx.x & 7;
  const int tid = threadIdx.x, lane = tid & 63, sub = tid >> 6;
  __shared__ float red[4][72];
  __shared__ float attnL[72];
  const float* src = part + (size_t)(b * 8 + p) * NCH * 72;
  float s0 = 0.0f, s1 = 0.0f;
  for (int ch = sub * (NCH / 4); ch < (sub + 1) * (NCH / 4); ch++) {
    s0 += src[ch * 72 + lane];
    if (lane < 8) s1 += src[ch * 72 + 64 + lane];
  }
  red[sub][lane] = s0;
  if (lane < 8) red[sub][64 + lane] = s1;
  __syncthreads();
  if (tid < 72) attnL[tid] = (red[0][tid] + red[1][tid]) + (red[2][tid] + red[3][tid]);
  __syncthreads();
  if (tid >= 64) {
    if (tid < 72) ws[WS_KSE + (b * 8 + p) * 8 + (tid - 64)] = attnL[tid] + EPSV;
    return;
  }
  const int o = tid;
  float wrow[8];
#pragma unroll
  for (int c = 0; c < 8; c++) wrow[c] = wo[o * 64 + p * 8 + c];
  float* Gp = ws + WS_G + (size_t)(b * 64 + p * 8) * 64;
#pragma unroll
  for (int m = 0; m < 8; m++) {
    float g = 0.0f;
#pragma unroll
    for (int c = 0; c < 8; c++) g = fmaf(attnL[m * 8 + c], wrow[c], g);
    Gp[m * 64 + o] = g;
  }
}

// ---------------- kernel 3: q, norm, fused out-projection (R15 best) ----------
__global__ void k3_main(const float* __restrict__ high,
                        const float* __restrict__ low,
                        const float* __restrict__ ws,
                        const float* __restrict__ bo,
                        float* __restrict__ out) {
  const int b = blockIdx.y, chunk = blockIdx.x;
  const int tid = threadIdx.x, lane = tid & 63;
  const int wu = __builtin_amdgcn_readfirstlane(tid >> 6);
  __shared__ float qsL[64 * KPX];                // 32 KB
  const float* srcb = ((wu < 4) ? high : low) + (size_t)b * 64 * NPIX + chunk * KPX;
  const float* wq  = ws + WS_WQT + wu * 512;
  const float* bq  = ws + WS_BQ + wu * 8;
  const float* kse = ws + WS_KSE + (b * 8 + wu) * 8;
  const float* Gb  = ws + WS_G + (size_t)b * 4096 + wu * 8;
  float qa[8][2];
#pragma unroll
  for (int m = 0; m < 8; m++) { qa[m][0] = bq[m]; qa[m][1] = bq[m]; }
#pragma unroll 8
  for (int c = 0; c < 64; c++) {
    float2 x = reinterpret_cast<const float2*>(srcb + (size_t)c * NPIX)[lane];
    const float* wr = wq + c * 8;
#pragma unroll
    for (int m = 0; m < 8; m++) {
      float w = wr[m];
      qa[m][0] = fmaf(w, x.x, qa[m][0]);
      qa[m][1] = fmaf(w, x.y, qa[m][1]);
    }
  }
  float s0 = 0.0f, s1 = 0.0f;
#pragma unroll
  for (int m = 0; m < 8; m++) {
    float km = kse[m];
    qa[m][0] = softplus_(qa[m][0]);
    qa[m][1] = softplus_(qa[m][1]);
    s0 = fmaf(qa[m][0], km, s0);
    s1 = fmaf(qa[m][1], km, s1);
  }
  const float r0 = 1.0f / s0, r1 = 1.0f / s1;
#pragma unroll
  for (int m = 0; m < 8; m++) {
    reinterpret_cast<float2*>(&qsL[(wu * 8 + m) * KPX])[lane] =
        make_float2(qa[m][0] * r0, qa[m][1] * r1);
  }
  __syncthreads();
  float acc[8][2];
#pragma unroll
  for (int j = 0; j < 8; j++) { acc[j][0] = bo[wu * 8 + j]; acc[j][1] = acc[j][0]; }
#pragma unroll 8
  for (int pm = 0; pm < 64; pm++) {
    float2 qv = reinterpret_cast<const float2*>(&qsL[pm * KPX])[lane];
    const float* gr = Gb + pm * 64;              // wave-uniform -> s_load
#pragma unroll
    for (int j = 0; j < 8; j++) {
      float g = gr[j];
      acc[j][0] = fmaf(g, qv.x, acc[j][0]);
      acc[j][1] = fmaf(g, qv.y, acc[j][1]);
    }
  }
  float* ob = out + (size_t)(b * 64 + wu * 8) * NPIX + chunk * KPX;
#pragma unroll
  for (int j = 0; j < 8; j++) {
    reinterpret_cast<float2*>(ob + (size_t)j * NPIX)[lane] =
        make_float2(acc[j][0], acc[j][1]);
  }
}

extern "C" void kernel_launch(void* const* d_in, const int* in_sizes, int n_in,
                              void* d_out, int out_size, void* d_ws, size_t ws_size,
                              hipStream_t stream) {
  const float* high    = (const float*)d_in[0];
  const float* low     = (const float*)d_in[1];
  const float* wq_high = (const float*)d_in[2];
  const float* bq_high = (const float*)d_in[3];
  const float* wq_low  = (const float*)d_in[4];
  const float* bq_low  = (const float*)d_in[5];
  const float* wk      = (const float*)d_in[6];
  const float* bk      = (const float*)d_in[7];
  const float* wv      = (const float*)d_in[8];
  const float* bv      = (const float*)d_in[9];
  const float* wo      = (const float*)d_in[10];
  const float* bo      = (const float*)d_in[11];
  float* ws  = (float*)d_ws;
  float* out = (float*)d_out;

  k0_pack<<<1, 256, 0, stream>>>(wq_high, bq_high, wq_low, bq_low, wk, bk, wv, bv, ws);
  dim3 grid1(NCH, NB);
  k1_kv<<<grid1, 256, 0, stream>>>(low, ws, ws + WS_PART);
  k2_g<<<64, 256, 0, stream>>>(ws + WS_PART, wo, ws);
  dim3 grid3(NCH, NB);
  k3_main<<<grid3, 512, 0, stream>>>(high, low, ws, bo, out);
}

// Round 18
// 112.777 us; speedup vs baseline: 1.3107x; 1.0879x over previous
//
#include <hip/hip_runtime.h>

// MCA linear attention. B=8, C=64, H=W=160, P=8 heads, d=8, N=25600.
// k1 AND k3 on MFMA (split-bf16, fp32-accurate). k2 also packs G MFMA frags.
#define NPIX  25600
#define NB    8
#define NCH   200    // pixel chunks per batch (128 px each)
#define KPX   128    // chunk pixels
#define EPSV  1e-6f

// workspace layout (float offsets)
#define WS_WQM   0        // Wq A-frags: 16 frags x 64 lanes x 8 bf16 = 4096 f
#define WS_BQM   4096     // [64 row] bias (row = head*8+m)
#define WS_WKVM  4160     // Wkv A-frags: 32 frags x 512 = 8192 f
#define WS_BKVM  12352    // [8 mt][16 row] bias
#define WS_KSE   12480    // [8 b][8 p][8 m] (+eps)
#define WS_PART  12992    // [64 bh][200 ch][72]
#define WS_GM    934592   // G A-frags: 8 b x 16 frags x 512 sh = 8 b x 4096 f

typedef __attribute__((ext_vector_type(8))) short short8v;
typedef __attribute__((ext_vector_type(4))) float f32x4v;

__device__ __forceinline__ unsigned short f2bf(float x) {   // RNE fp32->bf16 bits
  unsigned u = __float_as_uint(x);
  return (unsigned short)((u + 0x7FFFu + ((u >> 16) & 1u)) >> 16);
}
__device__ __forceinline__ float bf2f(unsigned short h) {
  return __uint_as_float(((unsigned)h) << 16);
}
__device__ __forceinline__ float softplus_(float x) {
  return (x > 20.0f) ? x : __logf(1.0f + __expf(x));
}

// ---------------- kernel 0: pack weight MFMA fragments ----------------
__global__ void k0_pack(const float* __restrict__ wq_high, const float* __restrict__ bq_high,
                        const float* __restrict__ wq_low,  const float* __restrict__ bq_low,
                        const float* __restrict__ wk, const float* __restrict__ bk,
                        const float* __restrict__ wv, const float* __restrict__ bv,
                        float* __restrict__ ws) {
  const int tid = threadIdx.x;
  // Wq A-frags (k3 phase A): A[row = mt*16 + l%16][c = ks*32 + (l/16)*8 + j]
  unsigned short* wqm = (unsigned short*)(ws + WS_WQM);
  for (int e = tid; e < 8192; e += 256) {
    int j = e & 7, l = (e >> 3) & 63, frag = e >> 9;
    int sp = frag & 1, ks = (frag >> 1) & 1, mt = frag >> 2;
    int row = mt * 16 + (l & 15), c = ks * 32 + (l >> 4) * 8 + j;
    int head = row >> 3, m = row & 7;
    float v = (head < 4) ? wq_high[(head * 8 + m) * 64 + c]
                         : wq_low[((head - 4) * 8 + m) * 64 + c];
    unsigned short hb = f2bf(v);
    wqm[e] = (sp == 0) ? hb : f2bf(v - bf2f(hb));
  }
  for (int e = tid; e < 64; e += 256) {          // bq by row
    int head = e >> 3, m = e & 7;
    ws[WS_BQM + e] = (head < 4) ? bq_high[head * 8 + m] : bq_low[(head - 4) * 8 + m];
  }
  // Wkv A-frags (k1 GEMM1), proven R17 layout
  unsigned short* wmp = (unsigned short*)(ws + WS_WKVM);
  for (int e = tid; e < 16384; e += 256) {
    int j = e & 7, l = (e >> 3) & 63, frag = e >> 9;
    int sp = frag & 1, ks = (frag >> 1) & 1, mt = frag >> 2;
    int row = l & 15, k32 = (l >> 4) * 8 + j, c = ks * 32 + k32;
    int head = (mt & 3) * 2 + (row >> 3), m = row & 7;
    float wv_ = (mt < 4) ? wk[(head * 8 + m) * 64 + c] : wv[(head * 8 + m) * 64 + c];
    unsigned short hb = f2bf(wv_);
    wmp[e] = (sp == 0) ? hb : f2bf(wv_ - bf2f(hb));
  }
  for (int e = tid; e < 128; e += 256) {
    int mt = e >> 4, row = e & 15;
    int head = (mt & 3) * 2 + (row >> 3), m = row & 7;
    ws[WS_BKVM + e] = (mt < 4) ? bk[head * 8 + m] : bv[head * 8 + m];
  }
}

// ---------------- kernel 1: MFMA k,v + attn partials (proven R17) ----------
__global__ __attribute__((amdgpu_waves_per_eu(1, 8)))
void k1_kv(const float* __restrict__ low,
           const float* __restrict__ ws,
           float* __restrict__ part) {
  const int b = blockIdx.y, chunk = blockIdx.x;
  const int tid = threadIdx.x, lane = tid & 63;
  const int w = __builtin_amdgcn_readfirstlane(tid >> 6);
  const int l15 = lane & 15, lg = lane >> 4;
  __shared__ float kvL[16384];                   // [128 feat][128 px] swizzled
  const float* lowb = low + (size_t)b * 64 * NPIX + chunk * KPX + w * 32;
  short8v xhi[2][2], xlo[2][2];
#pragma unroll
  for (int nt = 0; nt < 2; nt++)
#pragma unroll
    for (int ks = 0; ks < 2; ks++) {
      const float* xp = lowb + (size_t)(ks * 32 + lg * 8) * NPIX + nt * 16 + l15;
      float xs[8];
#pragma unroll
      for (int j = 0; j < 8; j++) xs[j] = xp[(size_t)j * NPIX];
#pragma unroll
      for (int j = 0; j < 8; j++) {
        unsigned short h = f2bf(xs[j]);
        xhi[nt][ks][j] = (short)h;
        xlo[nt][ks][j] = (short)f2bf(xs[j] - bf2f(h));
      }
    }
  const unsigned short* wm = (const unsigned short*)(ws + WS_WKVM);
  const float* bm = ws + WS_BKVM;
#pragma unroll
  for (int mt = 0; mt < 8; mt++) {
    f32x4v a0 = {0.f, 0.f, 0.f, 0.f}, a1 = {0.f, 0.f, 0.f, 0.f};
#pragma unroll
    for (int ks = 0; ks < 2; ks++) {
      short8v whi = *(const short8v*)(wm + (((mt * 4 + ks * 2 + 0) * 64) + lane) * 8);
      short8v wlo = *(const short8v*)(wm + (((mt * 4 + ks * 2 + 1) * 64) + lane) * 8);
      a0 = __builtin_amdgcn_mfma_f32_16x16x32_bf16(whi, xhi[0][ks], a0, 0, 0, 0);
      a0 = __builtin_amdgcn_mfma_f32_16x16x32_bf16(whi, xlo[0][ks], a0, 0, 0, 0);
      a0 = __builtin_amdgcn_mfma_f32_16x16x32_bf16(wlo, xhi[0][ks], a0, 0, 0, 0);
      a1 = __builtin_amdgcn_mfma_f32_16x16x32_bf16(whi, xhi[1][ks], a1, 0, 0, 0);
      a1 = __builtin_amdgcn_mfma_f32_16x16x32_bf16(whi, xlo[1][ks], a1, 0, 0, 0);
      a1 = __builtin_amdgcn_mfma_f32_16x16x32_bf16(wlo, xhi[1][ks], a1, 0, 0, 0);
    }
#pragma unroll
    for (int r = 0; r < 4; r++) {
      const int row = mt * 16 + lg * 4 + r;
      const float bb = bm[row];
      float v0 = a0[r] + bb, v1 = a1[r] + bb;
      if (mt < 4) { v0 = softplus_(v0); v1 = softplus_(v1); }
      const int px0 = w * 32 + l15, px1 = w * 32 + 16 + l15;
      kvL[row * 128 + ((((px0 >> 2) ^ (row & 7))) << 2) + (px0 & 3)] = v0;
      kvL[row * 128 + ((((px1 >> 2) ^ (row & 7))) << 2) + (px1 & 3)] = v1;
    }
  }
  __syncthreads();
  const int col = l15;
#pragma unroll
  for (int hh = 0; hh < 2; hh++) {
    const int h = w + hh * 4;
    f32x4v acc = {0.f, 0.f, 0.f, 0.f};
    const int arow = h * 8 + (l15 & 7);
    const int brow = 64 + h * 8 + (col < 8 ? col : 0);
#pragma unroll
    for (int ks = 0; ks < 4; ks++) {
      const int pxl = ks * 32 + lg * 8;
      const int sA = arow & 7;
      float4 af0 = *(const float4*)&kvL[arow * 128 + (((pxl >> 2) ^ sA) << 2)];
      float4 af1 = *(const float4*)&kvL[arow * 128 + ((((pxl >> 2) + 1) ^ sA) << 2)];
      float as[8] = {af0.x, af0.y, af0.z, af0.w, af1.x, af1.y, af1.z, af1.w};
      float bs[8];
      if (col < 8) {
        const int sB = brow & 7;
        float4 bf0 = *(const float4*)&kvL[brow * 128 + (((pxl >> 2) ^ sB) << 2)];
        float4 bf1 = *(const float4*)&kvL[brow * 128 + ((((pxl >> 2) + 1) ^ sB) << 2)];
        bs[0]=bf0.x; bs[1]=bf0.y; bs[2]=bf0.z; bs[3]=bf0.w;
        bs[4]=bf1.x; bs[5]=bf1.y; bs[6]=bf1.z; bs[7]=bf1.w;
      } else {
        const float fill = (col == 8) ? 1.0f : 0.0f;
#pragma unroll
        for (int j = 0; j < 8; j++) bs[j] = fill;
      }
      short8v ahi, alo, bhi, blo;
#pragma unroll
      for (int j = 0; j < 8; j++) {
        unsigned short ha = f2bf(as[j]);
        ahi[j] = (short)ha; alo[j] = (short)f2bf(as[j] - bf2f(ha));
        unsigned short hb = f2bf(bs[j]);
        bhi[j] = (short)hb; blo[j] = (short)f2bf(bs[j] - bf2f(hb));
      }
      acc = __builtin_amdgcn_mfma_f32_16x16x32_bf16(ahi, bhi, acc, 0, 0, 0);
      acc = __builtin_amdgcn_mfma_f32_16x16x32_bf16(ahi, blo, acc, 0, 0, 0);
      acc = __builtin_amdgcn_mfma_f32_16x16x32_bf16(alo, bhi, acc, 0, 0, 0);
    }
    if (lane < 32 && col <= 8) {
      float* pb = part + ((size_t)(b * 8 + h) * NCH + chunk) * 72;
#pragma unroll
      for (int r = 0; r < 4; r++) {
        const int rr = lg * 4 + r;
        if (col < 8) pb[rr * 8 + col] = acc[r];
        else         pb[64 + rr] = acc[r];
      }
    }
  }
}

// ---------------- kernel 2: reduce partials, ksumE, G MFMA frags ----------
__global__ void k2_g(const float* __restrict__ part, const float* __restrict__ wo,
                     float* __restrict__ ws) {
  const int b = blockIdx.x >> 3, p = blockIdx.x & 7;
  const int tid = threadIdx.x, lane = tid & 63, sub = tid >> 6;
  __shared__ float red[4][72];
  __shared__ float attnL[72];
  const float* src = part + (size_t)(b * 8 + p) * NCH * 72;
  float s0 = 0.0f, s1 = 0.0f;
  for (int ch = sub * (NCH / 4); ch < (sub + 1) * (NCH / 4); ch++) {
    s0 += src[ch * 72 + lane];
    if (lane < 8) s1 += src[ch * 72 + 64 + lane];
  }
  red[sub][lane] = s0;
  if (lane < 8) red[sub][64 + lane] = s1;
  __syncthreads();
  if (tid < 72) attnL[tid] = (red[0][tid] + red[1][tid]) + (red[2][tid] + red[3][tid]);
  __syncthreads();
  if (tid >= 64) {
    if (tid < 72) ws[WS_KSE + (b * 8 + p) * 8 + (tid - 64)] = attnL[tid] + EPSV;
    return;
  }
  const int o = tid;
  float wrow[8];
#pragma unroll
  for (int c = 0; c < 8; c++) wrow[c] = wo[o * 64 + p * 8 + c];
  // G row for (b, pm=p*8+m, o): g[m] = sum_c attn[m][c] * wo[o][p*8+c]
  unsigned short* gm = (unsigned short*)(ws + WS_GM) + (size_t)b * 8192;
  const int mt2 = o >> 4, lane_ = (p & 3) * 16 + (o & 15), ks = p >> 2;
  short8v hi8, lo8;
#pragma unroll
  for (int m = 0; m < 8; m++) {
    float g = 0.0f;
#pragma unroll
    for (int c = 0; c < 8; c++) g = fmaf(attnL[m * 8 + c], wrow[c], g);
    unsigned short hb = f2bf(g);
    hi8[m] = (short)hb;
    lo8[m] = (short)f2bf(g - bf2f(hb));
  }
  *(short8v*)(gm + (size_t)((mt2 * 4 + ks * 2 + 0) * 64 + lane_) * 8) = hi8;
  *(short8v*)(gm + (size_t)((mt2 * 4 + ks * 2 + 1) * 64 + lane_) * 8) = lo8;
}

// ---------------- kernel 3: MFMA q -> norm -> MFMA out-projection ----------
// 256 thr = 4 waves; block (chunk 128px, b). Phase A: q[64][128] =
// Wq.X (X = high for rows<32, low for rows>=32), split-bf16 MFMA, bias+
// softplus in C-regs -> swizzled qL. Norm: s[h][px] = sum_m q.kse -> rnL.
// Phase B: out[64 o][128 px] = G.(q*rn) via MFMA (G A-frags from k2), +bo.
__global__ __attribute__((amdgpu_waves_per_eu(1, 8)))
void k3_main(const float* __restrict__ high,
             const float* __restrict__ low,
             const float* __restrict__ ws,
             const float* __restrict__ bo,
             float* __restrict__ out) {
  const int b = blockIdx.y, chunk = blockIdx.x;
  const int tid = threadIdx.x, lane = tid & 63;
  const int w = __builtin_amdgcn_readfirstlane(tid >> 6);
  const int l15 = lane & 15, lg = lane >> 4;
  __shared__ float qL[8192];                     // [64 row][128 px] swizzled
  __shared__ float rnL[1024];                    // [8 h][128 px]
  const float* highb = high + (size_t)b * 64 * NPIX + chunk * KPX + w * 32;
  const float* lowb  = low  + (size_t)b * 64 * NPIX + chunk * KPX + w * 32;
  // ---- X B-frags for both sources ----
  short8v xhi[2][2][2], xlo[2][2][2];            // [src][nt][ks]
#pragma unroll
  for (int s = 0; s < 2; s++) {
    const float* srcb = (s == 0) ? highb : lowb;
#pragma unroll
    for (int nt = 0; nt < 2; nt++)
#pragma unroll
      for (int ks = 0; ks < 2; ks++) {
        const float* xp = srcb + (size_t)(ks * 32 + lg * 8) * NPIX + nt * 16 + l15;
        float xs[8];
#pragma unroll
        for (int j = 0; j < 8; j++) xs[j] = xp[(size_t)j * NPIX];
#pragma unroll
        for (int j = 0; j < 8; j++) {
          unsigned short h = f2bf(xs[j]);
          xhi[s][nt][ks][j] = (short)h;
          xlo[s][nt][ks][j] = (short)f2bf(xs[j] - bf2f(h));
        }
      }
  }
  const unsigned short* wqm = (const unsigned short*)(ws + WS_WQM);
  const float* bqm = ws + WS_BQM;
  // ---- phase A GEMM: rows mt*16.., mt 0-1 high, 2-3 low ----
#pragma unroll
  for (int mt = 0; mt < 4; mt++) {
    const int s = mt >> 1;
    f32x4v a0 = {0.f, 0.f, 0.f, 0.f}, a1 = {0.f, 0.f, 0.f, 0.f};
#pragma unroll
    for (int ks = 0; ks < 2; ks++) {
      short8v whi = *(const short8v*)(wqm + (((mt * 4 + ks * 2 + 0) * 64) + lane) * 8);
      short8v wlo = *(const short8v*)(wqm + (((mt * 4 + ks * 2 + 1) * 64) + lane) * 8);
      a0 = __builtin_amdgcn_mfma_f32_16x16x32_bf16(whi, xhi[s][0][ks], a0, 0, 0, 0);
      a0 = __builtin_amdgcn_mfma_f32_16x16x32_bf16(whi, xlo[s][0][ks], a0, 0, 0, 0);
      a0 = __builtin_amdgcn_mfma_f32_16x16x32_bf16(wlo, xhi[s][0][ks], a0, 0, 0, 0);
      a1 = __builtin_amdgcn_mfma_f32_16x16x32_bf16(whi, xhi[s][1][ks], a1, 0, 0, 0);
      a1 = __builtin_amdgcn_mfma_f32_16x16x32_bf16(whi, xlo[s][1][ks], a1, 0, 0, 0);
      a1 = __builtin_amdgcn_mfma_f32_16x16x32_bf16(wlo, xhi[s][1][ks], a1, 0, 0, 0);
    }
#pragma unroll
    for (int r = 0; r < 4; r++) {
      const int row = mt * 16 + lg * 4 + r;
      const float bb = bqm[row];
      float v0 = softplus_(a0[r] + bb), v1 = softplus_(a1[r] + bb);
      const int px0 = w * 32 + l15, px1 = w * 32 + 16 + l15;
      qL[row * 128 + ((((px0 >> 2) ^ (row & 7))) << 2) + (px0 & 3)] = v0;
      qL[row * 128 + ((((px1 >> 2) ^ (row & 7))) << 2) + (px1 & 3)] = v1;
    }
  }
  __syncthreads();
  // ---- norm: s[h][px] = sum_m q[h8+m][px]*kse[h][m]; rn = 1/s ----
  {
    const int px = tid & 127;
    const int hb = (tid >> 7) * 4;
#pragma unroll
    for (int h0 = 0; h0 < 4; h0++) {
      const int h = hb + h0;
      const float* ksep = ws + WS_KSE + (b * 8 + h) * 8;
      float s = 0.0f;
#pragma unroll
      for (int m = 0; m < 8; m++) {
        const int row = h * 8 + m;
        s = fmaf(qL[row * 128 + ((((px >> 2) ^ (row & 7))) << 2) + (px & 3)],
                 ksep[m], s);
      }
      rnL[h * 128 + px] = 1.0f / s;
    }
  }
  __syncthreads();
  // ---- phase B GEMM: out = G.(q*rn) + bo ----
  const unsigned short* gm = (const unsigned short*)(ws + WS_GM) + (size_t)b * 8192;
#pragma unroll
  for (int nt = 0; nt < 2; nt++) {
    const int px = w * 32 + nt * 16 + l15;
    short8v qhi[2], qlo[2];
#pragma unroll
    for (int ks = 0; ks < 2; ks++) {
      const float rn = rnL[(ks * 4 + lg) * 128 + px];
#pragma unroll
      for (int j = 0; j < 8; j++) {
        const int row = ks * 32 + lg * 8 + j;      // row & 7 == j
        float q = qL[row * 128 + ((((px >> 2) ^ j)) << 2) + (px & 3)] * rn;
        unsigned short h = f2bf(q);
        qhi[ks][j] = (short)h;
        qlo[ks][j] = (short)f2bf(q - bf2f(h));
      }
    }
    f32x4v acc[4];
#pragma unroll
    for (int mt2 = 0; mt2 < 4; mt2++) acc[mt2] = (f32x4v){0.f, 0.f, 0.f, 0.f};
#pragma unroll
    for (int mt2 = 0; mt2 < 4; mt2++) {
#pragma unroll
      for (int ks = 0; ks < 2; ks++) {
        short8v ghi = *(const short8v*)(gm + (size_t)((mt2 * 4 + ks * 2 + 0) * 64 + lane) * 8);
        short8v glo = *(const short8v*)(gm + (size_t)((mt2 * 4 + ks * 2 + 1) * 64 + lane) * 8);
        acc[mt2] = __builtin_amdgcn_mfma_f32_16x16x32_bf16(ghi, qhi[ks], acc[mt2], 0, 0, 0);
        acc[mt2] = __builtin_amdgcn_mfma_f32_16x16x32_bf16(ghi, qlo[ks], acc[mt2], 0, 0, 0);
        acc[mt2] = __builtin_amdgcn_mfma_f32_16x16x32_bf16(glo, qhi[ks], acc[mt2], 0, 0, 0);
      }
    }
    float* ob = out + ((size_t)b * 64) * NPIX + chunk * KPX + px;
#pragma unroll
    for (int mt2 = 0; mt2 < 4; mt2++)
#pragma unroll
      for (int r = 0; r < 4; r++) {
        const int o = mt2 * 16 + lg * 4 + r;
        ob[(size_t)o * NPIX] = acc[mt2][r] + bo[o];
      }
  }
}

extern "C" void kernel_launch(void* const* d_in, const int* in_sizes, int n_in,
                              void* d_out, int out_size, void* d_ws, size_t ws_size,
                              hipStream_t stream) {
  const float* high    = (const float*)d_in[0];
  const float* low     = (const float*)d_in[1];
  const float* wq_high = (const float*)d_in[2];
  const float* bq_high = (const float*)d_in[3];
  const float* wq_low  = (const float*)d_in[4];
  const float* bq_low  = (const float*)d_in[5];
  const float* wk      = (const float*)d_in[6];
  const float* bk      = (const float*)d_in[7];
  const float* wv      = (const float*)d_in[8];
  const float* bv      = (const float*)d_in[9];
  const float* wo      = (const float*)d_in[10];
  const float* bo      = (const float*)d_in[11];
  float* ws  = (float*)d_ws;
  float* out = (float*)d_out;

  k0_pack<<<1, 256, 0, stream>>>(wq_high, bq_high, wq_low, bq_low, wk, bk, wv, bv, ws);
  dim3 grid(NCH, NB);
  k1_kv<<<grid, 256, 0, stream>>>(low, ws, ws + WS_PART);
  k2_g<<<64, 256, 0, stream>>>(ws + WS_PART, wo, ws);
  k3_main<<<grid, 256, 0, stream>>>(high, low, ws, bo, out);
}